// Round 8
// baseline (884.547 us; speedup 1.0000x reference)
//
#include <hip/hip_runtime.h>

// Linear attention (elu+1 feature map), B=4 S=4096 D=2048 H=16 dk=128.
// bf16 MFMA, fp32 accumulate.
// Round 8: 32x32x16 MFMA + cross-phase read pipelining (reads for phase p+1
// issued before MFMA(p), compiler-counted lgkm waits, no manual drains),
// 1 barrier/phase, hoisted rolling stage pointers. Same 4-slot XOR-swizzled
// LDS layout and vmcnt ledger as R7 (gates vmcnt(6) at ph3/ph5/ph7).

#define D_MODEL 2048
#define SEQ     4096
#define BATCH   4
#define HEADS   16
#define DKH     128
#define M_TOK   16384   // BATCH*SEQ
#define NBH     64      // BATCH*HEADS

using frag8  = __attribute__((ext_vector_type(8))) short;   // 8 bf16 (4 VGPRs)
using f32x4  = __attribute__((ext_vector_type(4))) float;
using f32x16 = __attribute__((ext_vector_type(16))) float;

typedef __attribute__((address_space(1))) const unsigned int g_u32;
typedef __attribute__((address_space(3))) unsigned int       l_u32;

__device__ __forceinline__ unsigned short f2bf(float f) {
  unsigned u = __float_as_uint(f);
  u = u + 0x7fffu + ((u >> 16) & 1u);   // round-to-nearest-even
  return (unsigned short)(u >> 16);
}
__device__ __forceinline__ float bf2f(unsigned short h) {
  return __uint_as_float(((unsigned)h) << 16);
}

// ---- fp32 -> bf16 convert (vectorized) --------------------------------------
__global__ __launch_bounds__(256) void convert_f2bf_kernel(
    const float* __restrict__ in, unsigned short* __restrict__ out, int n4) {
  int i = blockIdx.x * 256 + threadIdx.x;
  if (i < n4) {
    float4 v = reinterpret_cast<const float4*>(in)[i];
    ushort4 o;
    o.x = f2bf(v.x); o.y = f2bf(v.y); o.z = f2bf(v.z); o.w = f2bf(v.w);
    reinterpret_cast<ushort4*>(out)[i] = o;
  }
}

// ============================================================================
// 256x256x(BK=64) 8-phase GEMM, C = A(256xK)*B(256xK)^T, bf16 NT, 32x32x16.
// 512 thr = 8 waves (2M x 4N); per-wave C = 128x64 = 4 quadrants x 2 n-tiles
// of 32x32 (f32x16 each). Slot s = one K-half (32 cols) of A(256) + B(256):
// A-part [0,8192) + B-part [8192,16384) elems. Layout: phys row p in [0,128),
// quad = side*4 + (c>>3) (side = r>>7), stored quad q' = quad ^ (p&7),
// elem = c&7. Stage writes linear w/ pre-XOR'd source (verified R5-R7).
// Tile u=2i -> slots 0/1, v=2i+1 -> slots 2/3.
// Per phase: [stage per ledger][gate][ds_reads for NEXT phase][8 MFMA][BAR].
// ============================================================================

#define STA(PAI, KC, SP, ST)                                                  \
  __builtin_amdgcn_global_load_lds((g_u32*)((PAI) + (ST) * lda32 + (KC)),     \
      (l_u32*)(sh + (SP) * 16384 + (ST) * 2048 + dstA), 16, 0, 0);
#define STB(PBI, KC, SLOT)                                                    \
  __builtin_amdgcn_global_load_lds((g_u32*)((PBI) + (KC)),                    \
      (l_u32*)(sh + (SLOT) * 16384 + dstB), 16, 0, 0);                        \
  __builtin_amdgcn_global_load_lds((g_u32*)((PBI) + ldb8 + (KC)),             \
      (l_u32*)(sh + (SLOT) * 16384 + dstB + 512), 16, 0, 0);

// A-frag reads for quadrant Q of slot-pair SB (s=0..3 over K=64)
#define RDA(dst, SB, Q)                                                       \
  dst[0] = *(const frag8*)(lds + (SB) * 16384 + (Q) * 2048 + tA0);            \
  dst[1] = *(const frag8*)(lds + (SB) * 16384 + (Q) * 2048 + tA1);            \
  dst[2] = *(const frag8*)(lds + ((SB) + 1) * 16384 + (Q) * 2048 + tA0);      \
  dst[3] = *(const frag8*)(lds + ((SB) + 1) * 16384 + (Q) * 2048 + tA1);
// B-frags for a whole tile (2 n-tiles x 4 k-steps)
#define RDB(dst, SB)                                                          \
  _Pragma("unroll") for (int t_ = 0; t_ < 2; ++t_) {                          \
    dst[t_ * 4 + 0] = *(const frag8*)(lds + (SB) * 16384 + t_ * 2048 + tB0);  \
    dst[t_ * 4 + 1] = *(const frag8*)(lds + (SB) * 16384 + t_ * 2048 + tB1);  \
    dst[t_ * 4 + 2] = *(const frag8*)(lds + ((SB)+1) * 16384 + t_ * 2048 + tB0); \
    dst[t_ * 4 + 3] = *(const frag8*)(lds + ((SB)+1) * 16384 + t_ * 2048 + tB1); \
  }
#define MM(Q, a_, b_)                                                         \
  __builtin_amdgcn_s_setprio(1);                                              \
  _Pragma("unroll") for (int s_ = 0; s_ < 4; ++s_)                            \
  _Pragma("unroll") for (int t_ = 0; t_ < 2; ++t_)                            \
    acc[Q][t_] = __builtin_amdgcn_mfma_f32_32x32x16_bf16(                     \
        a_[s_], b_[t_ * 4 + s_], acc[Q][t_], 0, 0, 0);                        \
  __builtin_amdgcn_s_setprio(0);
#define BAR __builtin_amdgcn_s_barrier()

// MODE: 0 = elu(v+bias[col])+1 -> bf16   (Q projection)
//       1 = elu(v+bias[row])+1 -> bf16   (K^T projection)
//       2 = v+bias[row]        -> bf16   (V^T projection)
//       3 = v+bias[col]        -> f32    (final output projection)
template <int MODE, bool XMAJOR>
__global__ __launch_bounds__(512, 2) void gemm256_nt_kernel(
    const unsigned short* __restrict__ A, long lda,
    const unsigned short* __restrict__ Bm, long ldb,
    void* __restrict__ Cv, long ldc,
    const float* __restrict__ bias, int K) {
  __shared__ unsigned short sh[65536];   // 128 KiB = 4 slots
  const int lane = threadIdx.x & 63, wid = threadIdx.x >> 6;
  const int wm = wid >> 2, wn = wid & 3;

  // T1 bijective XCD swizzle
  const int gx = gridDim.x, gy = gridDim.y;
  const int cpx = (gx * gy) >> 3;
  const int P = blockIdx.y * gx + blockIdx.x;
  const int Lw = (P & 7) * cpx + (P >> 3);
  int bx, by;
  if (XMAJOR) { bx = Lw / gy; by = Lw - bx * gy; }
  else        { by = Lw / gx; bx = Lw - by * gx; }

  const long m0 = (long)by * 256, n0 = (long)bx * 256;
  const unsigned short* Ablk = A + m0 * lda;
  const unsigned short* Bblk = Bm + n0 * ldb;
  const int NT = K >> 6, NI = NT >> 1;

  // read-side constants (32x32 frag: row/col = lane&31, k = (lane>>5)*8+j)
  const int l31 = lane & 31, l5 = lane >> 5, l7 = lane & 7;
  const unsigned short* lds = sh;
  const int qAe = (wm * 4 + l5) ^ l7;
  const int tA0 = l31 * 64 + qAe * 8;
  const int tA1 = l31 * 64 + (qAe ^ 2) * 8;
  const int qBe = ((wn >> 1) * 4 + l5) ^ l7;
  const int tB0 = 8192 + ((wn & 1) * 64 + l31) * 64 + qBe * 8;
  const int tB1 = 8192 + ((wn & 1) * 64 + l31) * 64 + (qBe ^ 2) * 8;

  // stage-side constants + rolling pointers
  const int sqd = (lane & 7) ^ (lane >> 3);
  const int scg = sqd & 3;
  const long lda32 = 32 * lda, ldb8 = 8 * ldb;
  const unsigned short* pa = Ablk +
      (long)((sqd >> 2) * 128 + (wid & 3) * 8 + (lane >> 3)) * lda +
      (wid >> 2) * 32 + scg * 8;
  const unsigned short* pb = Bblk +
      (long)((sqd >> 2) * 128 + wid * 16 + (lane >> 3)) * ldb + scg * 8;
  const int dstA = (wid >> 2) * 16384 + (wid & 3) * 512;
  const int dstB = 8192 + wid * 1024;

  f32x16 acc[4][2];
#pragma unroll
  for (int q = 0; q < 4; ++q)
#pragma unroll
    for (int t = 0; t < 2; ++t)
#pragma unroll
      for (int r = 0; r < 16; ++r) acc[q][t][r] = 0.f;

  frag8 aA[4], aB[4], bu[8], bv[8];

  // prologue: tile u complete (8 units), tile v all but A23 (6 units)
  STB(pb, 0, 0)
  STB(pb, 32, 1)
  STA(pa, 0, 0, 0) STA(pa, 0, 0, 1) STA(pa, 0, 0, 2) STA(pa, 0, 0, 3)
  if (NT > 1) {
    STB(pb, 64, 2)
    STB(pb, 96, 3)
    STA(pa, 64, 2, 0) STA(pa, 64, 2, 1)
  }
  asm volatile("s_waitcnt vmcnt(6)" ::: "memory");   // tile u landed
  RDA(aA, 0, 0)
  RDB(bu, 0)
  BAR;

  for (int i = 0; i < NI; ++i) {
    const bool wok = (i + 1) < NI;
    // ph0: u.q0 ; stage v.A23 ; read u.q1
    STA(pa, 64, 2, 2) STA(pa, 64, 2, 3)
    RDA(aB, 0, 1)
    MM(0, aA, bu)
    BAR;
    // ph1: u.q1 ; stage w.B0 ; read u.q2
    if (wok) { STB(pb, 128, 0) }
    RDA(aA, 0, 2)
    MM(1, aB, bu)
    BAR;
    // ph2: u.q2 ; stage w.B1 ; read u.q3
    if (wok) { STB(pb, 160, 1) }
    RDA(aB, 0, 3)
    MM(2, aA, bu)
    BAR;
    // ph3: u.q3 ; stage w.A01 ; gate v ; read v.q0 + v.B
    if (wok) { STA(pa, 128, 0, 0) STA(pa, 128, 0, 1) }
    if (wok) asm volatile("s_waitcnt vmcnt(6)" ::: "memory");
    else     asm volatile("s_waitcnt vmcnt(0)" ::: "memory");
    RDA(aA, 2, 0)
    RDB(bv, 2)
    MM(3, aB, bu)
    BAR;
    // ph4: v.q0 ; stage w.A23 ; read v.q1
    if (wok) { STA(pa, 128, 0, 2) STA(pa, 128, 0, 3) }
    RDA(aB, 2, 1)
    MM(0, aA, bv)
    BAR;
    // ph5: v.q1 ; stage x.B0 ; gate w.B ; read w.B (into bu, free since ph3)
    if (wok) {
      STB(pb, 192, 2)
      asm volatile("s_waitcnt vmcnt(6)" ::: "memory");
      RDB(bu, 0)
    }
    RDA(aA, 2, 2)
    MM(1, aB, bv)
    BAR;
    // ph6: v.q2 ; stage x.B1 ; read v.q3
    if (wok) { STB(pb, 224, 3) }
    RDA(aB, 2, 3)
    MM(2, aA, bv)
    BAR;
    // ph7: v.q3 ; stage x.A01 ; gate w.A ; read w.q0
    if (wok) {
      STA(pa, 192, 2, 0) STA(pa, 192, 2, 1)
      asm volatile("s_waitcnt vmcnt(6)" ::: "memory");
      RDA(aA, 0, 0)
    }
    MM(3, aB, bv)
    BAR;
    pa += 128; pb += 128;
  }

  // epilogue: 32x32 C/D: col = lane&31, row = (reg&3)+8*(reg>>2)+4*(lane>>5)
#pragma unroll
  for (int q = 0; q < 4; ++q)
#pragma unroll
    for (int t = 0; t < 2; ++t)
#pragma unroll
      for (int r = 0; r < 16; ++r) {
        long row = m0 + wm * 128 + q * 32 + (r & 3) + 8 * (r >> 2) + 4 * l5;
        long col = n0 + wn * 64 + t * 32 + l31;
        float v = acc[q][t][r];
        if (MODE == 0) {
          v += bias[col]; v = v > 0.f ? v + 1.f : __expf(v);
          ((unsigned short*)Cv)[row * ldc + col] = f2bf(v);
        } else if (MODE == 1) {
          v += bias[row]; v = v > 0.f ? v + 1.f : __expf(v);
          ((unsigned short*)Cv)[row * ldc + col] = f2bf(v);
        } else if (MODE == 2) {
          v += bias[row];
          ((unsigned short*)Cv)[row * ldc + col] = f2bf(v);
        } else {
          v += bias[col];
          ((float*)Cv)[row * ldc + col] = v;
        }
      }
}

// ============================================================================
// 128x128 path (attention core) — unchanged.
// ============================================================================
__device__ __forceinline__ void stage_tile(const unsigned short* __restrict__ G,
                                           long ld, unsigned short* __restrict__ L) {
  const int w = threadIdx.x >> 6, l = threadIdx.x & 63;
#pragma unroll
  for (int r = 0; r < 4; ++r) {
    const int chunk = w * 4 + r;
    const int row = chunk * 8 + (l >> 3);
    const int col = (l & 7) * 8;
    __builtin_amdgcn_global_load_lds((g_u32*)(G + (long)row * ld + col),
                                     (l_u32*)(L + chunk * 512), 16, 0, 0);
  }
}

__device__ __forceinline__ void gemm_mainloop(const unsigned short* __restrict__ A, long lda,
                                              const unsigned short* __restrict__ B, long ldb,
                                              int K, unsigned short* lA, unsigned short* lB,
                                              f32x4 acc[4][4]) {
  const int lane = threadIdx.x & 63;
  const int wid  = threadIdx.x >> 6;
  const int wr = wid >> 1, wc = wid & 1;
  const int lr = lane & 15, lh = lane >> 4;
  for (int k0 = 0; k0 < K; k0 += 64) {
    stage_tile(A + k0, lda, lA);
    stage_tile(B + k0, ldb, lB);
    __syncthreads();
#pragma unroll
    for (int kk = 0; kk < 64; kk += 32) {
      frag8 av[4], bv[4];
#pragma unroll
      for (int m = 0; m < 4; ++m)
        av[m] = *reinterpret_cast<const frag8*>(lA + (wr * 64 + m * 16 + lr) * 64 + kk + lh * 8);
#pragma unroll
      for (int n = 0; n < 4; ++n)
        bv[n] = *reinterpret_cast<const frag8*>(lB + (wc * 64 + n * 16 + lr) * 64 + kk + lh * 8);
#pragma unroll
      for (int m = 0; m < 4; ++m)
#pragma unroll
        for (int n = 0; n < 4; ++n)
          acc[m][n] = __builtin_amdgcn_mfma_f32_16x16x32_bf16(av[m], bv[n], acc[m][n], 0, 0, 0);
    }
    __syncthreads();
  }
}

#define ACC_INIT(acc)                                   \
  _Pragma("unroll") for (int m_ = 0; m_ < 4; ++m_)      \
  _Pragma("unroll") for (int n_ = 0; n_ < 4; ++n_)      \
      acc[m_][n_] = (f32x4){0.f, 0.f, 0.f, 0.f};

// ---- KV^T partials: per (bh, chunk) C[e,d] = sum_t V[t,e]K[t,d] over 512 t --
__global__ __launch_bounds__(256) void kvt_partial_kernel(
    const unsigned short* __restrict__ VT, const unsigned short* __restrict__ KT,
    float* __restrict__ part) {
  __shared__ unsigned short lA[128 * 64], lB[128 * 64];
  const int z = blockIdx.x;            // 0..511 = bh*8 + chunk
  const int bh = z >> 3, c = z & 7;
  const int b = bh >> 4, h = bh & 15;
  const long tOff = (long)b * SEQ + (long)c * 512;
  const unsigned short* A  = VT + (long)(h * DKH) * M_TOK + tOff;
  const unsigned short* Bm = KT + (long)(h * DKH) * M_TOK + tOff;
  f32x4 acc[4][4];
  ACC_INIT(acc);
  gemm_mainloop(A, M_TOK, Bm, M_TOK, 512, lA, lB, acc);
  const int lane = threadIdx.x & 63, wid = threadIdx.x >> 6;
  const int wr = wid >> 1, wc = wid & 1, lr = lane & 15, lh = lane >> 4;
  float* out = part + (long)z * (DKH * DKH);
#pragma unroll
  for (int m = 0; m < 4; ++m)
#pragma unroll
    for (int n = 0; n < 4; ++n)
#pragma unroll
      for (int r = 0; r < 4; ++r) {
        int row = wr * 64 + m * 16 + lh * 4 + r;   // e
        int col = wc * 64 + n * 16 + lr;           // d
        out[row * DKH + col] = acc[m][n][r];
      }
}

__global__ __launch_bounds__(256) void reduce_kvt_kernel(
    const float* __restrict__ part, unsigned short* __restrict__ kvt) {
  int i = blockIdx.x * 256 + threadIdx.x;          // over 64*16384
  if (i < NBH * DKH * DKH) {
    int bh = i >> 14, j = i & 16383;
    float s = 0.f;
#pragma unroll
    for (int c = 0; c < 8; ++c) s += part[(((long)bh * 8 + c) << 14) + j];
    kvt[i] = f2bf(s);
  }
}

// ---- K row sums ------------------------------------------------------------
__global__ __launch_bounds__(256) void ksum_kernel(const unsigned short* __restrict__ KT,
                                                   float* __restrict__ ksum) {
  int gr = blockIdx.x * 4 + (threadIdx.x >> 6);    // 0..8191 = bh*128+d
  int lane = threadIdx.x & 63;
  int bh = gr >> 7, d = gr & 127;
  int b = bh >> 4, h = bh & 15;
  const unsigned short* p = KT + (long)(h * DKH + d) * M_TOK + (long)b * SEQ;
  float s = 0.f;
#pragma unroll
  for (int i = 0; i < 8; ++i) {
    uint4 v = *reinterpret_cast<const uint4*>(p + (i * 64 + lane) * 8);
    unsigned w[4] = {v.x, v.y, v.z, v.w};
#pragma unroll
    for (int j = 0; j < 4; ++j) {
      s += bf2f((unsigned short)(w[j] & 0xffff));
      s += bf2f((unsigned short)(w[j] >> 16));
    }
  }
#pragma unroll
  for (int o = 32; o > 0; o >>= 1) s += __shfl_down(s, o);
  if (lane == 0) ksum[gr] = s;
}

// ---- qsum ------------------------------------------------------------------
__global__ __launch_bounds__(256) void qsum_kernel(const unsigned short* __restrict__ Q,
                                                   const float* __restrict__ ksum,
                                                   float* __restrict__ qsum) {
  int gr = blockIdx.x * 4 + (threadIdx.x >> 6);    // 0..262143 = bh*4096 + s
  int lane = threadIdx.x & 63;
  int bh = gr >> 12, s = gr & 4095;
  int b = bh >> 4, h = bh & 15;
  const unsigned short* q = Q + ((long)b * SEQ + s) * D_MODEL + h * DKH + lane * 2;
  unsigned u = *reinterpret_cast<const unsigned*>(q);
  const float* ks = ksum + bh * DKH + lane * 2;
  float sum = bf2f((unsigned short)(u & 0xffff)) * ks[0] +
              bf2f((unsigned short)(u >> 16)) * ks[1];
#pragma unroll
  for (int o = 32; o > 0; o >>= 1) sum += __shfl_down(sum, o);
  if (lane == 0) qsum[gr] = sum;
}

// ---- QKV -------------------------------------------------------------------
__global__ __launch_bounds__(256) void qkv_kernel(const unsigned short* __restrict__ Q,
                                                  const unsigned short* __restrict__ KVT,
                                                  const float* __restrict__ qsum,
                                                  unsigned short* __restrict__ attn) {
  __shared__ unsigned short lA[128 * 64], lB[128 * 64];
  const int z = blockIdx.z, b = z >> 4, h = z & 15;
  const long m0 = (long)blockIdx.y * 128;
  const unsigned short* A  = Q + ((long)b * SEQ + m0) * D_MODEL + h * DKH;
  const unsigned short* Bm = KVT + (long)z * (DKH * DKH);
  f32x4 acc[4][4];
  ACC_INIT(acc);
  gemm_mainloop(A, D_MODEL, Bm, DKH, DKH, lA, lB, acc);
  const int lane = threadIdx.x & 63, wid = threadIdx.x >> 6;
  const int wr = wid >> 1, wc = wid & 1, lr = lane & 15, lh = lane >> 4;
#pragma unroll
  for (int m = 0; m < 4; ++m)
#pragma unroll
    for (int n = 0; n < 4; ++n)
#pragma unroll
      for (int r = 0; r < 4; ++r) {
        long row = m0 + wr * 64 + m * 16 + lh * 4 + r;   // s in [0,4096)
        int  col = wc * 64 + n * 16 + lr;                // e in [0,128)
        float dnm = qsum[(long)z * SEQ + row] + 1e-8f;
        float v = acc[m][n][r] / dnm;
        attn[((long)b * SEQ + row) * D_MODEL + h * DKH + col] = f2bf(v);
      }
}

// ---- workspace layout (bytes) ----------------------------------------------
#define OFF_XB   0L
#define OFF_WQ   (OFF_XB + (long)M_TOK * D_MODEL * 2)
#define OFF_WK   (OFF_WQ + (long)D_MODEL * D_MODEL * 2)
#define OFF_WV   (OFF_WK + (long)D_MODEL * D_MODEL * 2)
#define OFF_WO   (OFF_WV + (long)D_MODEL * D_MODEL * 2)
#define OFF_QB   (OFF_WO + (long)D_MODEL * D_MODEL * 2)
#define OFF_KT   (OFF_QB + (long)M_TOK * D_MODEL * 2)
#define OFF_VT   (OFF_KT + (long)M_TOK * D_MODEL * 2)
#define OFF_PART (OFF_VT + (long)M_TOK * D_MODEL * 2)
#define OFF_KVT  (OFF_PART + (long)512 * DKH * DKH * 4)
#define OFF_KSUM (OFF_KVT + (long)NBH * DKH * DKH * 2)
#define OFF_QSUM (OFF_KSUM + (long)NBH * DKH * 4)
#define OFF_ATTN OFF_XB   // alias: x_bf16 dead after V^T projection

extern "C" void kernel_launch(void* const* d_in, const int* in_sizes, int n_in,
                              void* d_out, int out_size, void* d_ws, size_t ws_size,
                              hipStream_t stream) {
  const float* x  = (const float*)d_in[0];
  const float* wq = (const float*)d_in[1];
  const float* bq = (const float*)d_in[2];
  const float* wk = (const float*)d_in[3];
  const float* bk = (const float*)d_in[4];
  const float* wv = (const float*)d_in[5];
  const float* bv = (const float*)d_in[6];
  const float* wo = (const float*)d_in[7];
  const float* bo = (const float*)d_in[8];

  char* ws = (char*)d_ws;
  unsigned short* xb   = (unsigned short*)(ws + OFF_XB);
  unsigned short* wqb  = (unsigned short*)(ws + OFF_WQ);
  unsigned short* wkb  = (unsigned short*)(ws + OFF_WK);
  unsigned short* wvb  = (unsigned short*)(ws + OFF_WV);
  unsigned short* wob  = (unsigned short*)(ws + OFF_WO);
  unsigned short* Qb   = (unsigned short*)(ws + OFF_QB);
  unsigned short* KTb  = (unsigned short*)(ws + OFF_KT);
  unsigned short* VTb  = (unsigned short*)(ws + OFF_VT);
  float*          part = (float*)(ws + OFF_PART);
  unsigned short* KVTb = (unsigned short*)(ws + OFF_KVT);
  float*          ksum = (float*)(ws + OFF_KSUM);
  float*          qsum = (float*)(ws + OFF_QSUM);
  unsigned short* attn = (unsigned short*)(ws + OFF_ATTN);

  dim3 blk(256);
  dim3 blk5(512);

  // fp32 -> bf16
  convert_f2bf_kernel<<<(M_TOK * D_MODEL / 4) / 256, blk, 0, stream>>>(x, xb, M_TOK * D_MODEL / 4);
  convert_f2bf_kernel<<<(D_MODEL * D_MODEL / 4) / 256, blk, 0, stream>>>(wq, wqb, D_MODEL * D_MODEL / 4);
  convert_f2bf_kernel<<<(D_MODEL * D_MODEL / 4) / 256, blk, 0, stream>>>(wk, wkb, D_MODEL * D_MODEL / 4);
  convert_f2bf_kernel<<<(D_MODEL * D_MODEL / 4) / 256, blk, 0, stream>>>(wv, wvb, D_MODEL * D_MODEL / 4);
  convert_f2bf_kernel<<<(D_MODEL * D_MODEL / 4) / 256, blk, 0, stream>>>(wo, wob, D_MODEL * D_MODEL / 4);

  // Q = elu(x@Wq^T + bq)+1                       (M_TOK x 2048)
  gemm256_nt_kernel<0, false><<<dim3(D_MODEL / 256, M_TOK / 256), blk5, 0, stream>>>(
      xb, D_MODEL, wqb, D_MODEL, Qb, D_MODEL, bq, D_MODEL);
  // K^T = elu(Wk@x^T + bk)+1  (2048 x M_TOK), V^T = Wv@x^T + bv
  gemm256_nt_kernel<1, true><<<dim3(M_TOK / 256, D_MODEL / 256), blk5, 0, stream>>>(
      wkb, D_MODEL, xb, D_MODEL, KTb, M_TOK, bk, D_MODEL);
  gemm256_nt_kernel<2, true><<<dim3(M_TOK / 256, D_MODEL / 256), blk5, 0, stream>>>(
      wvb, D_MODEL, xb, D_MODEL, VTb, M_TOK, bv, D_MODEL);

  // KV^T per (b,h) via split-K partials + reduce
  kvt_partial_kernel<<<512, blk, 0, stream>>>(VTb, KTb, part);
  reduce_kvt_kernel<<<(NBH * DKH * DKH) / 256, blk, 0, stream>>>(part, KVTb);

  // K_sum and per-row denominators
  ksum_kernel<<<(NBH * DKH) / 4, blk, 0, stream>>>(KTb, ksum);
  qsum_kernel<<<(NBH * SEQ) / 4, blk, 0, stream>>>(Qb, ksum, qsum);

  // attn = (Q @ KV) / (Q . Ksum + 1e-8)   -> bf16 (aliases xb)
  qkv_kernel<<<dim3(1, SEQ / 128, NBH), blk, 0, stream>>>(Qb, KVTb, qsum, attn);

  // out = attn @ Wo^T + bo  -> fp32
  gemm256_nt_kernel<3, false><<<dim3(D_MODEL / 256, M_TOK / 256), blk5, 0, stream>>>(
      attn, D_MODEL, wob, D_MODEL, d_out, D_MODEL, bo, D_MODEL);
}

// Round 9
// 644.773 us; speedup vs baseline: 1.3719x; 1.3719x over previous
//
#include <hip/hip_runtime.h>

// Linear attention (elu+1 feature map), B=4 S=4096 D=2048 H=16 dk=128.
// bf16 MFMA, fp32 accumulate.
// Round 9: revert to R7 8-phase gemm (best, 140us); peel final K-iteration
// (branch-free steady-state loop); fuse ksum into K^T-proj epilogue (LDS
// reduce + per-row global atomicAdd) and qsum into Q-proj epilogue (exact
// in-block reduction, no atomics). Drops 2 kernels + 134 MB of re-reads.

#define D_MODEL 2048
#define SEQ     4096
#define BATCH   4
#define HEADS   16
#define DKH     128
#define M_TOK   16384   // BATCH*SEQ
#define NBH     64      // BATCH*HEADS

using frag8 = __attribute__((ext_vector_type(8))) short;   // 8 bf16 (4 VGPRs)
using f32x4 = __attribute__((ext_vector_type(4))) float;   // 4 fp32 acc

typedef __attribute__((address_space(1))) const unsigned int g_u32;
typedef __attribute__((address_space(3))) unsigned int       l_u32;

__device__ __forceinline__ unsigned short f2bf(float f) {
  unsigned u = __float_as_uint(f);
  u = u + 0x7fffu + ((u >> 16) & 1u);   // round-to-nearest-even
  return (unsigned short)(u >> 16);
}
__device__ __forceinline__ float bf2f(unsigned short h) {
  return __uint_as_float(((unsigned)h) << 16);
}

// ---- fp32 -> bf16 convert (vectorized) --------------------------------------
__global__ __launch_bounds__(256) void convert_f2bf_kernel(
    const float* __restrict__ in, unsigned short* __restrict__ out, int n4) {
  int i = blockIdx.x * 256 + threadIdx.x;
  if (i < n4) {
    float4 v = reinterpret_cast<const float4*>(in)[i];
    ushort4 o;
    o.x = f2bf(v.x); o.y = f2bf(v.y); o.z = f2bf(v.z); o.w = f2bf(v.w);
    reinterpret_cast<ushort4*>(out)[i] = o;
  }
}

// ============================================================================
// 256x256x(BK=64) 8-phase GEMM (R7 structure), C = A(256xK)*B(256xK)^T.
// ============================================================================

#define ST_B(GB, LD, SLOT, KC)                                                \
  _Pragma("unroll") for (int j_ = 0; j_ < 2; ++j_)                            \
    __builtin_amdgcn_global_load_lds(                                         \
        (g_u32*)((GB) + (srow + wid * 16 + j_ * 8 + (lane >> 3)) * (LD)       \
                 + (KC) + scg * 8),                                           \
        (l_u32*)(sh + (SLOT) * 16384 + 8192 + (wid * 16 + j_ * 8) * 64),      \
        16, 0, 0);

#define ST_A(GA, LD, SP, ST, KC)                                              \
    __builtin_amdgcn_global_load_lds(                                         \
        (g_u32*)((GA) + (srow + (ST) * 32 + (wid & 3) * 8 + (lane >> 3)) * (LD) \
                 + (KC) + (wid >> 2) * 32 + scg * 8),                         \
        (l_u32*)(sh + ((SP) + (wid >> 2)) * 16384 +                           \
                 ((ST) * 32 + (wid & 3) * 8) * 64),                           \
        16, 0, 0);

#define RD_A(S0, S1, Q)                                                       \
  a0[0] = *(const frag8*)(lds + (S0) * 16384 + tA + (Q) * 2048);              \
  a0[1] = *(const frag8*)(lds + (S0) * 16384 + tA + (Q) * 2048 + 1024);       \
  a1[0] = *(const frag8*)(lds + (S1) * 16384 + tA + (Q) * 2048);              \
  a1[1] = *(const frag8*)(lds + (S1) * 16384 + tA + (Q) * 2048 + 1024);

#define RD_B(D0, D1, S0, S1)                                                  \
  _Pragma("unroll") for (int n_ = 0; n_ < 4; ++n_) {                          \
    D0[n_] = *(const frag8*)(lds + (S0) * 16384 + tB + n_ * 1024);            \
    D1[n_] = *(const frag8*)(lds + (S1) * 16384 + tB + n_ * 1024);            \
  }

#define MM8(AQ, B0, B1)                                                       \
  __builtin_amdgcn_s_setprio(1);                                              \
  _Pragma("unroll") for (int j_ = 0; j_ < 2; ++j_)                            \
  _Pragma("unroll") for (int n_ = 0; n_ < 4; ++n_)                            \
    acc[(AQ) + j_][n_] = __builtin_amdgcn_mfma_f32_16x16x32_bf16(             \
        a0[j_], B0[n_], acc[(AQ) + j_][n_], 0, 0, 0);                         \
  _Pragma("unroll") for (int j_ = 0; j_ < 2; ++j_)                            \
  _Pragma("unroll") for (int n_ = 0; n_ < 4; ++n_)                            \
    acc[(AQ) + j_][n_] = __builtin_amdgcn_mfma_f32_16x16x32_bf16(             \
        a1[j_], B1[n_], acc[(AQ) + j_][n_], 0, 0, 0);                         \
  __builtin_amdgcn_s_setprio(0);

#define BAR __builtin_amdgcn_s_barrier()
#define LG0                                                                   \
  asm volatile("s_waitcnt lgkmcnt(0)" ::: "memory");                          \
  __builtin_amdgcn_sched_barrier(0)

// MODE: 0 = elu+1 -> bf16, fused qsum (aux = ksum input; writes qsum)
//       1 = elu+1 -> bf16, fused ksum (aux = ksum output, atomicAdd)
//       2 = v+bias[row] -> bf16
//       3 = v+bias[col] -> f32
template <int MODE, bool XMAJOR>
__global__ __launch_bounds__(512, 2) void gemm256_nt_kernel(
    const unsigned short* __restrict__ A, long lda,
    const unsigned short* __restrict__ Bm, long ldb,
    void* __restrict__ Cv, long ldc,
    const float* __restrict__ bias, float* __restrict__ aux,
    float* __restrict__ qsum, int K) {
  __shared__ unsigned short sh[65536];   // 128 KiB = 4 slots
  const int lane = threadIdx.x & 63, wid = threadIdx.x >> 6;
  const int wm = wid >> 2, wn = wid & 3;
  const int lr = lane & 15, lh = lane >> 4;

  // T1 bijective XCD swizzle
  const int gx = gridDim.x, gy = gridDim.y;
  const int cpx = (gx * gy) >> 3;
  const int P = blockIdx.y * gx + blockIdx.x;
  const int Lw = (P & 7) * cpx + (P >> 3);
  int bx, by;
  if (XMAJOR) { bx = Lw / gy; by = Lw - bx * gy; }
  else        { by = Lw / gx; bx = Lw - by * gx; }

  const long m0 = (long)by * 256, n0 = (long)bx * 256;
  const unsigned short* Ablk = A + m0 * lda;
  const unsigned short* Bblk = Bm + n0 * ldb;
  const int NT = K >> 6;

  const int qA = (wm * 4 + lh) ^ (lr & 7);
  const int qB = ((wn >> 1) * 4 + lh) ^ (lr & 7);
  const unsigned short* lds = sh;
  const int tA = lr * 64 + qA * 8;
  const int tB = 8192 + ((wn & 1) * 64 + lr) * 64 + qB * 8;

  const int sqd = (lane & 7) ^ (lane >> 3);
  const int scg = sqd & 3;
  const long srow = (long)((sqd >> 2) * 128);

  f32x4 acc[8][4];
#pragma unroll
  for (int m = 0; m < 8; ++m)
#pragma unroll
    for (int n = 0; n < 4; ++n) acc[m][n] = (f32x4){0.f, 0.f, 0.f, 0.f};

  frag8 a0[2], a1[2], bu0[4], bu1[4], bv0[4], bv1[4];

  // prologue: tile 0 complete (8 units), tile 1 all but A-strips 2,3
  ST_B(Bblk, ldb, 0, 0)
  ST_B(Bblk, ldb, 1, 32)
  ST_A(Ablk, lda, 0, 0, 0) ST_A(Ablk, lda, 0, 1, 0)
  ST_A(Ablk, lda, 0, 2, 0) ST_A(Ablk, lda, 0, 3, 0)
  ST_B(Bblk, ldb, 2, 64)
  ST_B(Bblk, ldb, 3, 96)
  ST_A(Ablk, lda, 2, 0, 64) ST_A(Ablk, lda, 2, 1, 64)
  asm volatile("s_waitcnt vmcnt(6)" ::: "memory");   // tile 0 landed
  BAR;

  const int NI = NT >> 1;
  // ---- main loop: branch-free steady state (i = 0..NI-2) ----
  for (int i = 0; i < NI - 1; ++i) {
    const int kv = i * 128 + 64, kw = i * 128 + 128, kx = i * 128 + 192;
    // ph0: u q0
    RD_A(0, 1, 0)
    RD_B(bu0, bu1, 0, 1)
    ST_A(Ablk, lda, 2, 2, kv) ST_A(Ablk, lda, 2, 3, kv)
    asm volatile("s_waitcnt lgkmcnt(8)" ::: "memory");
    BAR; LG0;
    MM8(0, bu0, bu1)
    BAR;
    // ph1
    RD_A(0, 1, 1)
    ST_B(Bblk, ldb, 0, kw)
    BAR; LG0;
    MM8(2, bu0, bu1)
    BAR;
    // ph2
    RD_A(0, 1, 2)
    ST_B(Bblk, ldb, 1, kw + 32)
    BAR; LG0;
    MM8(4, bu0, bu1)
    BAR;
    // ph3 ; gate v
    RD_A(0, 1, 3)
    ST_A(Ablk, lda, 0, 0, kw) ST_A(Ablk, lda, 0, 1, kw)
    asm volatile("s_waitcnt vmcnt(6)" ::: "memory");
    BAR; LG0;
    MM8(6, bu0, bu1)
    BAR;
    // ph4: v q0
    RD_A(2, 3, 0)
    RD_B(bv0, bv1, 2, 3)
    ST_A(Ablk, lda, 0, 2, kw) ST_A(Ablk, lda, 0, 3, kw)
    asm volatile("s_waitcnt lgkmcnt(8)" ::: "memory");
    BAR; LG0;
    MM8(0, bv0, bv1)
    BAR;
    // ph5
    RD_A(2, 3, 1)
    ST_B(Bblk, ldb, 2, kx)
    BAR; LG0;
    MM8(2, bv0, bv1)
    BAR;
    // ph6
    RD_A(2, 3, 2)
    ST_B(Bblk, ldb, 3, kx + 32)
    BAR; LG0;
    MM8(4, bv0, bv1)
    BAR;
    // ph7 ; gate w
    RD_A(2, 3, 3)
    ST_A(Ablk, lda, 2, 0, kx) ST_A(Ablk, lda, 2, 1, kx)
    asm volatile("s_waitcnt vmcnt(6)" ::: "memory");
    BAR; LG0;
    MM8(6, bv0, bv1)
    BAR;
  }
  // ---- final iteration (no staging beyond v.A23) ----
  {
    const int kv = (NI - 1) * 128 + 64;
    RD_A(0, 1, 0)
    RD_B(bu0, bu1, 0, 1)
    ST_A(Ablk, lda, 2, 2, kv) ST_A(Ablk, lda, 2, 3, kv)
    asm volatile("s_waitcnt lgkmcnt(8)" ::: "memory");
    BAR; LG0;
    MM8(0, bu0, bu1)
    BAR;
    RD_A(0, 1, 1)
    BAR; LG0;
    MM8(2, bu0, bu1)
    BAR;
    RD_A(0, 1, 2)
    BAR; LG0;
    MM8(4, bu0, bu1)
    BAR;
    RD_A(0, 1, 3)
    asm volatile("s_waitcnt vmcnt(0)" ::: "memory");
    BAR; LG0;
    MM8(6, bu0, bu1)
    BAR;
    RD_A(2, 3, 0)
    RD_B(bv0, bv1, 2, 3)
    asm volatile("s_waitcnt lgkmcnt(8)" ::: "memory");
    BAR; LG0;
    MM8(0, bv0, bv1)
    BAR;
    RD_A(2, 3, 1)
    BAR; LG0;
    MM8(2, bv0, bv1)
    BAR;
    RD_A(2, 3, 2)
    BAR; LG0;
    MM8(4, bv0, bv1)
    BAR;
    RD_A(2, 3, 3)
    BAR; LG0;
    MM8(6, bv0, bv1)
    BAR;
  }

  // ---- epilogue (acc[m]: rows (m>>1)*32 + (m&1)*16 of the wave's 128) ----
  float* red = (float*)sh;   // LDS free after final BAR
  if (MODE == 0 || MODE == 1) {
    if (threadIdx.x < 512) { red[threadIdx.x] = 0.f; }
    __syncthreads();
  }
  float ksv[4];
  if (MODE == 0) {
    const long b2048 = (m0 >> 12) * 2048;
#pragma unroll
    for (int n = 0; n < 4; ++n)
      ksv[n] = aux[b2048 + n0 + wn * 64 + n * 16 + lr];
  }
#pragma unroll
  for (int m = 0; m < 8; ++m)
#pragma unroll
    for (int r = 0; r < 4; ++r) {
      const int lrow = wm * 128 + (m >> 1) * 32 + (m & 1) * 16 + lh * 4 + r;
      const long row = m0 + lrow;
      float part = 0.f;
#pragma unroll
      for (int n = 0; n < 4; ++n) {
        long col = n0 + wn * 64 + n * 16 + lr;
        float v = acc[m][n][r];
        if (MODE == 0) {
          v += bias[col]; v = v > 0.f ? v + 1.f : __expf(v);
          unsigned short us = f2bf(v);
          ((unsigned short*)Cv)[row * ldc + col] = us;
          part += bf2f(us) * ksv[n];
        } else if (MODE == 1) {
          v += bias[row]; v = v > 0.f ? v + 1.f : __expf(v);
          unsigned short us = f2bf(v);
          ((unsigned short*)Cv)[row * ldc + col] = us;
          part += bf2f(us);
        } else if (MODE == 2) {
          v += bias[row];
          ((unsigned short*)Cv)[row * ldc + col] = f2bf(v);
        } else {
          v += bias[col];
          ((float*)Cv)[row * ldc + col] = v;
        }
      }
      if (MODE == 0 || MODE == 1) {
#pragma unroll
        for (int s = 1; s < 16; s <<= 1) part += __shfl_xor(part, s);
        if (lr == 0) {
          if (MODE == 0) atomicAdd(&red[lrow * 2 + (wn >> 1)], part);
          else           atomicAdd(&red[lrow], part);
        }
      }
    }
  if (MODE == 0) {
    __syncthreads();
    if (threadIdx.x < 512) {
      const int lrow = threadIdx.x >> 1, hh = threadIdx.x & 1;
      const long grow = m0 + lrow;
      qsum[((grow >> 12) * 16 + (n0 >> 7) + hh) * (long)SEQ + (grow & 4095)] =
          red[threadIdx.x];
    }
  } else if (MODE == 1) {
    __syncthreads();
    if (threadIdx.x < 256)
      atomicAdd(&aux[(n0 >> 12) * 2048 + m0 + threadIdx.x], red[threadIdx.x]);
  }
}

// ============================================================================
// 128x128 path (attention core) — unchanged.
// ============================================================================
__device__ __forceinline__ void stage_tile(const unsigned short* __restrict__ G,
                                           long ld, unsigned short* __restrict__ L) {
  const int w = threadIdx.x >> 6, l = threadIdx.x & 63;
#pragma unroll
  for (int r = 0; r < 4; ++r) {
    const int chunk = w * 4 + r;
    const int row = chunk * 8 + (l >> 3);
    const int col = (l & 7) * 8;
    __builtin_amdgcn_global_load_lds((g_u32*)(G + (long)row * ld + col),
                                     (l_u32*)(L + chunk * 512), 16, 0, 0);
  }
}

__device__ __forceinline__ void gemm_mainloop(const unsigned short* __restrict__ A, long lda,
                                              const unsigned short* __restrict__ B, long ldb,
                                              int K, unsigned short* lA, unsigned short* lB,
                                              f32x4 acc[4][4]) {
  const int lane = threadIdx.x & 63;
  const int wid  = threadIdx.x >> 6;
  const int wr = wid >> 1, wc = wid & 1;
  const int lr = lane & 15, lh = lane >> 4;
  for (int k0 = 0; k0 < K; k0 += 64) {
    stage_tile(A + k0, lda, lA);
    stage_tile(B + k0, ldb, lB);
    __syncthreads();
#pragma unroll
    for (int kk = 0; kk < 64; kk += 32) {
      frag8 av[4], bv[4];
#pragma unroll
      for (int m = 0; m < 4; ++m)
        av[m] = *reinterpret_cast<const frag8*>(lA + (wr * 64 + m * 16 + lr) * 64 + kk + lh * 8);
#pragma unroll
      for (int n = 0; n < 4; ++n)
        bv[n] = *reinterpret_cast<const frag8*>(lB + (wc * 64 + n * 16 + lr) * 64 + kk + lh * 8);
#pragma unroll
      for (int m = 0; m < 4; ++m)
#pragma unroll
        for (int n = 0; n < 4; ++n)
          acc[m][n] = __builtin_amdgcn_mfma_f32_16x16x32_bf16(av[m], bv[n], acc[m][n], 0, 0, 0);
    }
    __syncthreads();
  }
}

#define ACC_INIT(acc)                                   \
  _Pragma("unroll") for (int m_ = 0; m_ < 4; ++m_)      \
  _Pragma("unroll") for (int n_ = 0; n_ < 4; ++n_)      \
      acc[m_][n_] = (f32x4){0.f, 0.f, 0.f, 0.f};

// ---- KV^T partials ---------------------------------------------------------
__global__ __launch_bounds__(256) void kvt_partial_kernel(
    const unsigned short* __restrict__ VT, const unsigned short* __restrict__ KT,
    float* __restrict__ part) {
  __shared__ unsigned short lA[128 * 64], lB[128 * 64];
  const int z = blockIdx.x;            // 0..511 = bh*8 + chunk
  const int bh = z >> 3, c = z & 7;
  const int b = bh >> 4, h = bh & 15;
  const long tOff = (long)b * SEQ + (long)c * 512;
  const unsigned short* A  = VT + (long)(h * DKH) * M_TOK + tOff;
  const unsigned short* Bm = KT + (long)(h * DKH) * M_TOK + tOff;
  f32x4 acc[4][4];
  ACC_INIT(acc);
  gemm_mainloop(A, M_TOK, Bm, M_TOK, 512, lA, lB, acc);
  const int lane = threadIdx.x & 63, wid = threadIdx.x >> 6;
  const int wr = wid >> 1, wc = wid & 1, lr = lane & 15, lh = lane >> 4;
  float* out = part + (long)z * (DKH * DKH);
#pragma unroll
  for (int m = 0; m < 4; ++m)
#pragma unroll
    for (int n = 0; n < 4; ++n)
#pragma unroll
      for (int r = 0; r < 4; ++r) {
        int row = wr * 64 + m * 16 + lh * 4 + r;   // e
        int col = wc * 64 + n * 16 + lr;           // d
        out[row * DKH + col] = acc[m][n][r];
      }
}

__global__ __launch_bounds__(256) void reduce_kvt_kernel(
    const float* __restrict__ part, unsigned short* __restrict__ kvt) {
  int i = blockIdx.x * 256 + threadIdx.x;          // over 64*16384
  if (i < NBH * DKH * DKH) {
    int bh = i >> 14, j = i & 16383;
    float s = 0.f;
#pragma unroll
    for (int c = 0; c < 8; ++c) s += part[(((long)bh * 8 + c) << 14) + j];
    kvt[i] = f2bf(s);
  }
}

// ---- QKV -------------------------------------------------------------------
__global__ __launch_bounds__(256) void qkv_kernel(const unsigned short* __restrict__ Q,
                                                  const unsigned short* __restrict__ KVT,
                                                  const float* __restrict__ qsum,
                                                  unsigned short* __restrict__ attn) {
  __shared__ unsigned short lA[128 * 64], lB[128 * 64];
  const int z = blockIdx.z, b = z >> 4, h = z & 15;
  const long m0 = (long)blockIdx.y * 128;
  const unsigned short* A  = Q + ((long)b * SEQ + m0) * D_MODEL + h * DKH;
  const unsigned short* Bm = KVT + (long)z * (DKH * DKH);
  f32x4 acc[4][4];
  ACC_INIT(acc);
  gemm_mainloop(A, D_MODEL, Bm, DKH, DKH, lA, lB, acc);
  const int lane = threadIdx.x & 63, wid = threadIdx.x >> 6;
  const int wr = wid >> 1, wc = wid & 1, lr = lane & 15, lh = lane >> 4;
#pragma unroll
  for (int m = 0; m < 4; ++m)
#pragma unroll
    for (int n = 0; n < 4; ++n)
#pragma unroll
      for (int r = 0; r < 4; ++r) {
        long row = m0 + wr * 64 + m * 16 + lh * 4 + r;   // s in [0,4096)
        int  col = wc * 64 + n * 16 + lr;                // e in [0,128)
        float dnm = qsum[(long)z * SEQ + row] + 1e-8f;
        float v = acc[m][n][r] / dnm;
        attn[((long)b * SEQ + row) * D_MODEL + h * DKH + col] = f2bf(v);
      }
}

// ---- workspace layout (bytes) ----------------------------------------------
#define OFF_XB   0L
#define OFF_WQ   (OFF_XB + (long)M_TOK * D_MODEL * 2)
#define OFF_WK   (OFF_WQ + (long)D_MODEL * D_MODEL * 2)
#define OFF_WV   (OFF_WK + (long)D_MODEL * D_MODEL * 2)
#define OFF_WO   (OFF_WV + (long)D_MODEL * D_MODEL * 2)
#define OFF_QB   (OFF_WO + (long)D_MODEL * D_MODEL * 2)
#define OFF_KT   (OFF_QB + (long)M_TOK * D_MODEL * 2)
#define OFF_VT   (OFF_KT + (long)M_TOK * D_MODEL * 2)
#define OFF_PART (OFF_VT + (long)M_TOK * D_MODEL * 2)
#define OFF_KVT  (OFF_PART + (long)512 * DKH * DKH * 4)
#define OFF_KSUM (OFF_KVT + (long)NBH * DKH * DKH * 2)
#define OFF_QSUM (OFF_KSUM + (long)NBH * DKH * 4)
#define OFF_ATTN OFF_XB   // alias: x_bf16 dead after V^T projection

extern "C" void kernel_launch(void* const* d_in, const int* in_sizes, int n_in,
                              void* d_out, int out_size, void* d_ws, size_t ws_size,
                              hipStream_t stream) {
  const float* x  = (const float*)d_in[0];
  const float* wq = (const float*)d_in[1];
  const float* bq = (const float*)d_in[2];
  const float* wk = (const float*)d_in[3];
  const float* bk = (const float*)d_in[4];
  const float* wv = (const float*)d_in[5];
  const float* bv = (const float*)d_in[6];
  const float* wo = (const float*)d_in[7];
  const float* bo = (const float*)d_in[8];

  char* ws = (char*)d_ws;
  unsigned short* xb   = (unsigned short*)(ws + OFF_XB);
  unsigned short* wqb  = (unsigned short*)(ws + OFF_WQ);
  unsigned short* wkb  = (unsigned short*)(ws + OFF_WK);
  unsigned short* wvb  = (unsigned short*)(ws + OFF_WV);
  unsigned short* wob  = (unsigned short*)(ws + OFF_WO);
  unsigned short* Qb   = (unsigned short*)(ws + OFF_QB);
  unsigned short* KTb  = (unsigned short*)(ws + OFF_KT);
  unsigned short* VTb  = (unsigned short*)(ws + OFF_VT);
  float*          part = (float*)(ws + OFF_PART);
  unsigned short* KVTb = (unsigned short*)(ws + OFF_KVT);
  float*          ksum = (float*)(ws + OFF_KSUM);
  float*          qsum = (float*)(ws + OFF_QSUM);
  unsigned short* attn = (unsigned short*)(ws + OFF_ATTN);

  dim3 blk(256);
  dim3 blk5(512);

  // fp32 -> bf16
  convert_f2bf_kernel<<<(M_TOK * D_MODEL / 4) / 256, blk, 0, stream>>>(x, xb, M_TOK * D_MODEL / 4);
  convert_f2bf_kernel<<<(D_MODEL * D_MODEL / 4) / 256, blk, 0, stream>>>(wq, wqb, D_MODEL * D_MODEL / 4);
  convert_f2bf_kernel<<<(D_MODEL * D_MODEL / 4) / 256, blk, 0, stream>>>(wk, wkb, D_MODEL * D_MODEL / 4);
  convert_f2bf_kernel<<<(D_MODEL * D_MODEL / 4) / 256, blk, 0, stream>>>(wv, wvb, D_MODEL * D_MODEL / 4);
  convert_f2bf_kernel<<<(D_MODEL * D_MODEL / 4) / 256, blk, 0, stream>>>(wo, wob, D_MODEL * D_MODEL / 4);

  // ksum must start at zero (K^T-proj accumulates into it)
  hipMemsetAsync(ksum, 0, NBH * DKH * sizeof(float), stream);

  // K^T = elu(Wk@x^T + bk)+1  (2048 x M_TOK), fused ksum
  gemm256_nt_kernel<1, true><<<dim3(M_TOK / 256, D_MODEL / 256), blk5, 0, stream>>>(
      wkb, D_MODEL, xb, D_MODEL, KTb, M_TOK, bk, ksum, nullptr, D_MODEL);
  // Q = elu(x@Wq^T + bq)+1  (M_TOK x 2048), fused qsum (reads ksum)
  gemm256_nt_kernel<0, false><<<dim3(D_MODEL / 256, M_TOK / 256), blk5, 0, stream>>>(
      xb, D_MODEL, wqb, D_MODEL, Qb, D_MODEL, bq, ksum, qsum, D_MODEL);
  // V^T = Wv@x^T + bv
  gemm256_nt_kernel<2, true><<<dim3(M_TOK / 256, D_MODEL / 256), blk5, 0, stream>>>(
      wvb, D_MODEL, xb, D_MODEL, VTb, M_TOK, bv, nullptr, nullptr, D_MODEL);

  // KV^T per (b,h) via split-K partials + reduce
  kvt_partial_kernel<<<512, blk, 0, stream>>>(VTb, KTb, part);
  reduce_kvt_kernel<<<(NBH * DKH * DKH) / 256, blk, 0, stream>>>(part, KVTb);

  // attn = (Q @ KV) / (Q . Ksum + 1e-8)   -> bf16 (aliases xb)
  qkv_kernel<<<dim3(1, SEQ / 128, NBH), blk, 0, stream>>>(Qb, KVTb, qsum, attn);

  // out = attn @ Wo^T + bo  -> fp32
  gemm256_nt_kernel<3, false><<<dim3(D_MODEL / 256, M_TOK / 256), blk5, 0, stream>>>(
      attn, D_MODEL, wob, D_MODEL, d_out, D_MODEL, bo, nullptr, nullptr, D_MODEL);
}